// Round 13
// baseline (2321.556 us; speedup 1.0000x reference)
//
#include <hip/hip_runtime.h>
#include <hip/hip_bf16.h>

#define BS 64
#define SEQ 200
#define NSK 4096
#define DS 256
#define SM 64
#define NROWS (BS*SEQ)

typedef __attribute__((ext_vector_type(8))) short bf16x8;
typedef __attribute__((ext_vector_type(4))) float f32x4;
typedef unsigned long long u64;

__device__ __forceinline__ float sigf(float x){ return 1.0f/(1.0f+expf(-x)); }
__device__ __forceinline__ float fast_sig(float x){ return 1.0f/(1.0f+__expf(-x)); }
__device__ __forceinline__ float fast_tanh(float x){
  float t = __expf(-2.0f*fabsf(x));
  float r = (1.0f - t)/(1.0f + t);
  return copysignf(r, x);
}
__device__ __forceinline__ short f2bf(float x){
  unsigned int u = __float_as_uint(x);
  unsigned int r = (u + 0x7fffu + ((u >> 16) & 1u)) >> 16;
  return (short)r;
}
__device__ __forceinline__ float bf2f(unsigned short s){
  return __uint_as_float(((unsigned int)s) << 16);
}

// ---------------- weight pre-conversion f32 -> bf16 -------------------------
__global__ __launch_bounds__(256) void k_cvtw(
    const float* __restrict__ Wa, const float* __restrict__ We,
    const float* __restrict__ Wadd, const float* __restrict__ Wf,
    const float* __restrict__ Wih, ushort* __restrict__ out)
{
  const int bid = blockIdx.x;
  const float* src; size_t rbase; int lb;
  if      (bid < 64) { src = Wa;   rbase = 0;      lb = bid; }
  else if (bid < 96) { src = We;   rbase = 131072; lb = bid - 64; }
  else if (bid < 128){ src = Wadd; rbase = 196608; lb = bid - 96; }
  else if (bid < 192){ src = Wf;   rbase = 262144; lb = bid - 128; }
  else               { src = Wih;  rbase = 393216; lb = bid - 192; }
  const int idx = (lb*256 + threadIdx.x) * 8;
  float4 a1 = *(const float4*)(src + idx);
  float4 a2 = *(const float4*)(src + idx + 4);
  bf16x8 v;
  v[0]=f2bf(a1.x); v[1]=f2bf(a1.y); v[2]=f2bf(a1.z); v[3]=f2bf(a1.w);
  v[4]=f2bf(a2.x); v[5]=f2bf(a2.y); v[6]=f2bf(a2.z); v[7]=f2bf(a2.w);
  *(bf16x8*)(out + rbase + idx) = v;
}

// ---------------- Kernel A: gather k,v + attention softmax w ----------------
__global__ __launch_bounds__(256) void k_gather_attn(
    const int* __restrict__ q, const int* __restrict__ r,
    const float* __restrict__ k_emb, const float* __restrict__ x_emb,
    const float* __restrict__ Mk,
    float* __restrict__ X2, float* __restrict__ vbuf, float* __restrict__ wbuf)
{
  __shared__ float ks[4][DS];
  const int tid = threadIdx.x;
  const int wv = tid >> 6, ln = tid & 63;
  const int row = blockIdx.x * 4 + wv;
  const int b = row / SEQ, s = row % SEQ;
  const int qi = q[b*SEQ + s];
  const int ri = r[b*SEQ + s];
  const float4* kr = (const float4*)(k_emb + (size_t)qi * DS);
  const float4* vr = (const float4*)(x_emb + ((size_t)qi + (size_t)NSK * ri) * DS);
  float4 kv = kr[ln];
  float4 vv = vr[ln];
  ((float4*)(X2 + (size_t)row*512 + DS))[ln] = kv;
  ((float4*)(vbuf + (size_t)row*DS))[ln] = vv;
  *((float4*)&ks[wv][ln*4]) = kv;
  __syncthreads();
  const float4* mkr = (const float4*)(Mk + (size_t)ln * DS);
  float a0=0.f,a1=0.f,a2=0.f,a3=0.f;
  #pragma unroll 8
  for (int d4=0; d4<DS/4; d4++){
    float4 m4 = mkr[d4];
    float4 k4 = *((const float4*)&ks[wv][d4*4]);
    a0 += m4.x*k4.x; a1 += m4.y*k4.y; a2 += m4.z*k4.z; a3 += m4.w*k4.w;
  }
  float lg = (a0+a1)+(a2+a3);
  float mx = lg;
  #pragma unroll
  for (int off=32; off; off>>=1) mx = fmaxf(mx, __shfl_xor(mx, off));
  float ex = expf(lg - mx);
  float sm = ex;
  #pragma unroll
  for (int off=32; off; off>>=1) sm += __shfl_xor(sm, off);
  wbuf[(size_t)row*SM + ln] = ex / sm;
}

// ---------------- bf16 MFMA GEMM: C = act(A @ W^T + bias [+bias2]) ----------
template<int ACT, int ABF, int OUT, int NT>
__global__ __launch_bounds__(256) void k_gemm2(
    const void* __restrict__ A0, int lda0, int K0,
    const void* __restrict__ A1, int lda1, int K1,
    const ushort* __restrict__ W, const float* __restrict__ bias,
    const float* __restrict__ bias2,
    void* __restrict__ C, int N)
{
  const int K = K0 + K1;
  __shared__ __align__(16) char As[64*80];
  __shared__ __align__(16) char Bs[NT][64*80];
  const int tid = threadIdx.x;
  const int l = tid & 63, w = tid >> 6;
  const int m0 = blockIdx.x * 64, n0 = blockIdx.y * (64*NT);
  const int mh = w >> 1, nh = w & 1;
  const int srow = tid >> 2, sseg = tid & 3;

  f32x4 acc[NT][2][2];
  #pragma unroll
  for (int nt=0; nt<NT; nt++)
    #pragma unroll
    for (int i=0;i<2;i++)
      #pragma unroll
      for (int j=0;j<2;j++) acc[nt][i][j] = (f32x4){0.f,0.f,0.f,0.f};

  for (int k0=0; k0<K; k0+=32){
    const int kk = k0 + sseg*8;
    bf16x8 av;
    if (ABF){
      const ushort* ap = (kk < K0) ? (const ushort*)A0 + (size_t)(m0+srow)*lda0 + kk
                                   : (const ushort*)A1 + (size_t)(m0+srow)*lda1 + (kk-K0);
      av = *(const bf16x8*)ap;
    } else {
      const float* ap = (kk < K0) ? (const float*)A0 + (size_t)(m0+srow)*lda0 + kk
                                  : (const float*)A1 + (size_t)(m0+srow)*lda1 + (kk-K0);
      float4 a1 = *(const float4*)ap;
      float4 a2 = *(const float4*)(ap+4);
      av[0]=f2bf(a1.x); av[1]=f2bf(a1.y); av[2]=f2bf(a1.z); av[3]=f2bf(a1.w);
      av[4]=f2bf(a2.x); av[5]=f2bf(a2.y); av[6]=f2bf(a2.z); av[7]=f2bf(a2.w);
    }
    *(bf16x8*)(As + srow*80 + ((sseg ^ (srow&3))*16)) = av;
    #pragma unroll
    for (int nt=0; nt<NT; nt++){
      bf16x8 bv = *(const bf16x8*)(W + (size_t)(n0 + nt*64 + srow)*K + kk);
      *(bf16x8*)(Bs[nt] + srow*80 + ((sseg ^ (srow&3))*16)) = bv;
    }
    __syncthreads();
    bf16x8 af[2];
    #pragma unroll
    for (int mi=0; mi<2; mi++){
      const int row = mh*32 + mi*16 + (l&15);
      af[mi] = *(const bf16x8*)(As + row*80 + (((l>>4) ^ (row&3))*16));
    }
    #pragma unroll
    for (int nt=0; nt<NT; nt++){
      bf16x8 bf[2];
      #pragma unroll
      for (int ni=0; ni<2; ni++){
        const int row = nh*32 + ni*16 + (l&15);
        bf[ni] = *(const bf16x8*)(Bs[nt] + row*80 + (((l>>4) ^ (row&3))*16));
      }
      #pragma unroll
      for (int mi=0; mi<2; mi++)
        #pragma unroll
        for (int ni=0; ni<2; ni++)
          acc[nt][mi][ni] = __builtin_amdgcn_mfma_f32_16x16x32_bf16(af[mi], bf[ni], acc[nt][mi][ni], 0,0,0);
    }
    __syncthreads();
  }
  #pragma unroll
  for (int nt=0; nt<NT; nt++){
    #pragma unroll
    for (int mi=0; mi<2; mi++){
      #pragma unroll
      for (int ni=0; ni<2; ni++){
        const int n = n0 + nt*64 + nh*32 + ni*16 + (l&15);
        float bsum = bias[n] + (bias2 ? bias2[n] : 0.f);
        #pragma unroll
        for (int j=0;j<4;j++){
          const int m = m0 + mh*32 + mi*16 + (l>>4)*4 + j;
          float v = acc[nt][mi][ni][j] + bsum;
          if (ACT==1) v = sigf(v);
          else if (ACT==2) v = tanhf(v);
          if (OUT==0)      ((float*)C)[(size_t)m*N + n] = v;
          else if (OUT==1) ((ushort*)C)[(size_t)m*N + n] = (ushort)f2bf(v);
          else             ((ushort*)C)[(size_t)m*N + ((n&255)*4 + (n>>8))] = (ushort)f2bf(v);
        }
      }
    }
  }
}

// ---------------- fused erase/add GEMM (A bf16, B pre-converted bf16) -------
__global__ __launch_bounds__(256) void k_gemm_ea(
    const ushort* __restrict__ A, const ushort* __restrict__ We_bf,
    const float* __restrict__ b_e, const ushort* __restrict__ Wadd_bf,
    const float* __restrict__ b_add,
    float* __restrict__ ebuf, float* __restrict__ abuf)
{
  __shared__ __align__(16) char As[64*80];
  __shared__ __align__(16) char Bse[64*80];
  __shared__ __align__(16) char Bsa[64*80];
  const int tid = threadIdx.x;
  const int l = tid & 63, w = tid >> 6;
  const int m0 = blockIdx.x * 64, n0 = blockIdx.y * 64;
  const int mh = w >> 1, nh = w & 1;
  const int srow = tid >> 2, sseg = tid & 3;

  f32x4 acce[2][2], acca[2][2];
  #pragma unroll
  for (int i=0;i<2;i++)
    #pragma unroll
    for (int j=0;j<2;j++){ acce[i][j]=(f32x4){0.f,0.f,0.f,0.f}; acca[i][j]=(f32x4){0.f,0.f,0.f,0.f}; }

  for (int k0=0; k0<DS; k0+=32){
    const int kk = k0 + sseg*8;
    bf16x8 av = *(const bf16x8*)(A + (size_t)(m0+srow)*DS + kk);
    *(bf16x8*)(As + srow*80 + ((sseg ^ (srow&3))*16)) = av;
    bf16x8 be = *(const bf16x8*)(We_bf + (size_t)(n0+srow)*DS + kk);
    *(bf16x8*)(Bse + srow*80 + ((sseg ^ (srow&3))*16)) = be;
    bf16x8 ba = *(const bf16x8*)(Wadd_bf + (size_t)(n0+srow)*DS + kk);
    *(bf16x8*)(Bsa + srow*80 + ((sseg ^ (srow&3))*16)) = ba;
    __syncthreads();
    bf16x8 af[2], bfe[2], bfa[2];
    #pragma unroll
    for (int mi=0; mi<2; mi++){
      const int row = mh*32 + mi*16 + (l&15);
      af[mi] = *(const bf16x8*)(As + row*80 + (((l>>4) ^ (row&3))*16));
    }
    #pragma unroll
    for (int ni=0; ni<2; ni++){
      const int row = nh*32 + ni*16 + (l&15);
      bfe[ni] = *(const bf16x8*)(Bse + row*80 + (((l>>4) ^ (row&3))*16));
      bfa[ni] = *(const bf16x8*)(Bsa + row*80 + (((l>>4) ^ (row&3))*16));
    }
    #pragma unroll
    for (int mi=0; mi<2; mi++)
      #pragma unroll
      for (int ni=0; ni<2; ni++){
        acce[mi][ni] = __builtin_amdgcn_mfma_f32_16x16x32_bf16(af[mi], bfe[ni], acce[mi][ni], 0,0,0);
        acca[mi][ni] = __builtin_amdgcn_mfma_f32_16x16x32_bf16(af[mi], bfa[ni], acca[mi][ni], 0,0,0);
      }
    __syncthreads();
  }
  #pragma unroll
  for (int mi=0; mi<2; mi++){
    #pragma unroll
    for (int ni=0; ni<2; ni++){
      const int n = n0 + nh*32 + ni*16 + (l&15);
      const float be = b_e[n], ba = b_add[n];
      #pragma unroll
      for (int j=0;j<4;j++){
        const int m = m0 + mh*32 + mi*16 + (l>>4)*4 + j;
        ebuf[(size_t)m*DS + n] = sigf(acce[mi][ni][j] + be);
        abuf[(size_t)m*DS + n] = tanhf(acca[mi][ni][j] + ba);
      }
    }
  }
}

// ---------------- Memory scan (sequential over t, next-step prefetch) -------
__global__ __launch_bounds__(256) void k_scan(
    const float* __restrict__ wbuf, const float* __restrict__ ebuf,
    const float* __restrict__ abuf, const float* __restrict__ Mv0,
    float* __restrict__ X2)
{
  const int b = blockIdx.x;
  const int d = threadIdx.x;
  __shared__ float ws[SM];
  float mem[SM];
  #pragma unroll
  for (int m=0;m<SM;m++) mem[m] = Mv0[m*DS + d];
  const size_t rb = (size_t)b*SEQ;
  float wn = (d < SM) ? wbuf[rb*SM + d] : 0.f;
  float en = ebuf[rb*DS + d];
  float an = abuf[rb*DS + d];
  for (int t=0;t<SEQ;t++){
    if (d < SM) ws[d] = wn;
    const float e = en, a = an;
    __syncthreads();
    if (t+1 < SEQ){
      wn = (d < SM) ? wbuf[(rb+t+1)*SM + d] : 0.f;
      en = ebuf[(rb+t+1)*DS + d];
      an = abuf[(rb+t+1)*DS + d];
    }
    float r0=0.f,r1=0.f,r2=0.f,r3=0.f;
    #pragma unroll
    for (int m=0;m<SM;m+=4){
      float w0=ws[m], w1=ws[m+1], w2=ws[m+2], w3=ws[m+3];
      r0 += w0*mem[m];   mem[m]   += w0*fmaf(-e, mem[m],   a);
      r1 += w1*mem[m+1]; mem[m+1] += w1*fmaf(-e, mem[m+1], a);
      r2 += w2*mem[m+2]; mem[m+2] += w2*fmaf(-e, mem[m+2], a);
      r3 += w3*mem[m+3]; mem[m+3] += w3*fmaf(-e, mem[m+3], a);
    }
    X2[(rb+t)*512 + d] = (r0+r1)+(r2+r3);
    __syncthreads();
  }
}

// ---------------- Full-W single-block LSTM (16 waves, no communication) -----
// 4 blocks x 1024 threads (16 waves). Block p owns batches [16p,+16) and holds
// the FULL W_hh: wave w owns dims [16w,+16) of all 4 gates = wfr[4][8] = 32
// frags = 128 VGPRs -- the EXACT per-wave footprint of the proven R9 kernel.
// h double-buffered in 16KB LDS; ONE barrier per step; no cross-block traffic.
__global__ __launch_bounds__(1024, 1) void k_lstm_full(
    const ushort* __restrict__ gin2, const float* __restrict__ W_hh,
    const float* __restrict__ hx, const float* __restrict__ cx,
    short* __restrict__ hhist)
{
  __shared__ short hsm[2][16*256];   // 2 x 8KB, 512B rows, XOR-swizzled

  const int p   = blockIdx.x;
  const int tid = threadIdx.x;
  const int l   = tid & 63;
  const int w   = tid >> 6;          // 0..15: dim-slice [16w, 16w+16)

  // W_hh B-fragments (R9-verified layout): G = gt*256 + w*16 + col,
  // k = kt*32 + (l>>4)*8 + j
  bf16x8 wfr[4][8];
  {
    const int col  = l & 15;
    const int krow = (l >> 4) * 8;
    #pragma unroll
    for (int gt=0; gt<4; gt++){
      const int G = gt*256 + w*16 + col;
      const float* wrow = W_hh + (size_t)G*256;
      #pragma unroll
      for (int kt=0; kt<8; kt++){
        const int k0 = kt*32 + krow;
        float4 wa = *(const float4*)(wrow + k0);
        float4 wb = *(const float4*)(wrow + k0 + 4);
        bf16x8 f;
        f[0]=f2bf(wa.x); f[1]=f2bf(wa.y); f[2]=f2bf(wa.z); f[3]=f2bf(wa.w);
        f[4]=f2bf(wb.x); f[5]=f2bf(wb.y); f[6]=f2bf(wb.z); f[7]=f2bf(wb.w);
        wfr[gt][kt] = f;
      }
    }
  }

  const int gdim = w*16 + (l & 15);     // this lane's dim, 0..255
  float c_[4];
  {
    float c0 = cx[gdim];
    #pragma unroll
    for (int r=0;r<4;r++) c_[r] = c0;
  }

  // stage hx into hsm[0] (full 256 dims x 16 rows)
  if (tid < 256){
    const int row = tid >> 4, seg = tid & 15;
    #pragma unroll
    for (int u=0; u<2; u++){
      const int kb = seg*32 + u*16;
      const int d0 = kb >> 1;
      float4 ha = *(const float4*)(hx + d0);
      float4 hb = *(const float4*)(hx + d0 + 4);
      bf16x8 v;
      v[0]=f2bf(ha.x); v[1]=f2bf(ha.y); v[2]=f2bf(ha.z); v[3]=f2bf(ha.w);
      v[4]=f2bf(hb.x); v[5]=f2bf(hb.y); v[6]=f2bf(hb.z); v[7]=f2bf(hb.w);
      *(bf16x8*)((char*)hsm[0] + row*512 + (kb ^ ((row&7)<<4))) = v;
    }
  }

  // prefetch gin[t=0]: one u64 per batch (4 gates for this lane's dim)
  u64 gpre[4];
  #pragma unroll
  for (int r=0; r<4; r++){
    const int b = p*16 + (l>>4)*4 + r;
    gpre[r] = *(const u64*)(gin2 + ((size_t)(b*SEQ))*1024 + gdim*4);
  }

  for (int t=0; t<SEQ; t++){
    __syncthreads();   // hsm[t&1] fully staged (and prior-step reads done)
    const int cur = t & 1;

    f32x4 acc[4];
    #pragma unroll
    for (int gt=0; gt<4; gt++) acc[gt] = (f32x4){0.f,0.f,0.f,0.f};
    const int r0 = l & 15;
    #pragma unroll
    for (int kt=0; kt<8; kt++){
      const int kbyte = kt*64 + (l>>4)*16;
      bf16x8 a = *(const bf16x8*)((const char*)hsm[cur] + r0*512 + (kbyte ^ ((r0&7)<<4)));
      #pragma unroll
      for (int gt=0; gt<4; gt++)
        acc[gt] = __builtin_amdgcn_mfma_f32_16x16x32_bf16(a, wfr[gt][kt], acc[gt], 0,0,0);
    }

    #pragma unroll
    for (int r=0; r<4; r++){
      const int bat = (l>>4)*4 + r;            // block-local batch 0..15
      const int b = p*16 + bat;
      const u64 gv = gpre[r];
      float iv = acc[0][r] + bf2f((unsigned short)(gv       & 0xffffu));
      float fv = acc[1][r] + bf2f((unsigned short)((gv>>16) & 0xffffu));
      float gg = acc[2][r] + bf2f((unsigned short)((gv>>32) & 0xffffu));
      float ov = acc[3][r] + bf2f((unsigned short)((gv>>48) & 0xffffu));
      float cc = fast_sig(fv)*c_[r] + fast_sig(iv)*fast_tanh(gg);
      c_[r] = cc;
      float h = fast_sig(ov)*fast_tanh(cc);
      unsigned short hb = (unsigned short)f2bf(h);
      hhist[((size_t)(b*SEQ + t))*256 + gdim] = (short)hb;
      // write h(t) into the OTHER buffer; safe vs concurrent reads of hsm[cur]
      *(short*)((char*)hsm[cur^1] + bat*512 + ((gdim*2) ^ ((bat&7)<<4))) = (short)hb;
    }

    if (t == SEQ-1) break;

    // prefetch gin[t+1]; latency hides behind next barrier + MFMA
    #pragma unroll
    for (int r=0; r<4; r++){
      const int b = p*16 + (l>>4)*4 + r;
      gpre[r] = *(const u64*)(gin2 + ((size_t)(b*SEQ + t+1))*1024 + gdim*4);
    }
  }
}

// ---------------- p output: sigmoid(h . W_p + b_p) --------------------------
__global__ __launch_bounds__(256) void k_pout(
    const short* __restrict__ hhist, const float* __restrict__ W_p,
    const float* __restrict__ b_p, float* __restrict__ out)
{
  const int tid = threadIdx.x;
  const int row = blockIdx.x*4 + (tid>>6);
  const int ln = tid & 63;
  ushort4 hv = ((const ushort4*)(hhist + (size_t)row*256))[ln];
  float4 wp = ((const float4*)W_p)[ln];
  float s = bf2f(hv.x)*wp.x + bf2f(hv.y)*wp.y + bf2f(hv.z)*wp.z + bf2f(hv.w)*wp.w;
  #pragma unroll
  for (int off=32; off; off>>=1) s += __shfl_xor(s, off);
  if (ln == 0) out[row] = sigf(s + b_p[0]);
}

extern "C" void kernel_launch(void* const* d_in, const int* in_sizes, int n_in,
                              void* d_out, int out_size, void* d_ws, size_t ws_size,
                              hipStream_t stream)
{
  const int*   q     = (const int*)d_in[0];
  const int*   r     = (const int*)d_in[1];
  const float* k_emb = (const float*)d_in[2];
  const float* x_emb = (const float*)d_in[3];
  const float* Mk    = (const float*)d_in[4];
  const float* Mv0   = (const float*)d_in[5];
  const float* W_a   = (const float*)d_in[6];
  const float* b_a   = (const float*)d_in[7];
  const float* W_e   = (const float*)d_in[8];
  const float* b_e   = (const float*)d_in[9];
  const float* W_add = (const float*)d_in[10];
  const float* b_add = (const float*)d_in[11];
  const float* W_f   = (const float*)d_in[12];
  const float* b_f   = (const float*)d_in[13];
  const float* hx    = (const float*)d_in[14];
  const float* cx    = (const float*)d_in[15];
  const float* W_ih  = (const float*)d_in[16];
  const float* b_ih  = (const float*)d_in[17];
  const float* W_hh  = (const float*)d_in[18];
  const float* b_hh  = (const float*)d_in[19];
  const float* W_p   = (const float*)d_in[20];
  const float* b_p   = (const float*)d_in[21];
  float* out = (float*)d_out;

  // byte-offset workspace layout
  char* base = (char*)d_ws;
  float*  vbuf  = (float*)(base);                          // 13.1MB
  ushort* webuf = (ushort*)(base + 13107200);              // 6.55MB
  float*  ebuf  = (float*)(base + 19660800);               // 13.1MB
  float*  abuf  = (float*)(base + 32768000);               // 13.1MB
  float*  X2    = (float*)(base + 45875200);               // 26.2MB [reads|k]
  float*  wbuf  = (float*)(base + 72089600);               // 3.3MB
  ushort* fbuf  = (ushort*)(base + 75366400);              // 6.55MB
  ushort* gin2  = (ushort*)(base);                         // 26.2MB overlay (vbuf..ebuf dead)
  short*  hhist = (short*)fbuf;                            // overlay (fbuf dead post-gin)
  ushort* wbf   = (ushort*)(base + 82000000);              // 1.31MB bf16 weights

  ushort* wa_bf   = wbf;
  ushort* we_bf   = wbf + 131072;
  ushort* wadd_bf = wbf + 196608;
  ushort* wf_bf   = wbf + 262144;
  ushort* wih_bf  = wbf + 393216;

  k_cvtw<<<320, 256, 0, stream>>>(W_a, W_e, W_add, W_f, W_ih, wbf);
  k_gather_attn<<<NROWS/4, 256, 0, stream>>>(q, r, k_emb, x_emb, Mk, X2, vbuf, wbuf);
  // we = [k|v] @ W_a^T + b_a  -> bf16
  k_gemm2<0,0,1,1><<<dim3(NROWS/64, 4), 256, 0, stream>>>(X2+DS, 512, DS, vbuf, DS, DS, wa_bf, b_a, nullptr, webuf, DS);
  // erase/add fused
  k_gemm_ea<<<dim3(NROWS/64, 4), 256, 0, stream>>>(webuf, we_bf, b_e, wadd_bf, b_add, ebuf, abuf);
  // memory scan -> reads into X2[:,0:256]
  k_scan<<<BS, DS, 0, stream>>>(wbuf, ebuf, abuf, Mv0, X2);
  // f = tanh([reads|k] @ W_f^T + b_f) -> bf16
  k_gemm2<2,0,1,1><<<dim3(NROWS/64, 4), 256, 0, stream>>>(X2, 512, DS, X2+DS, 512, DS, wf_bf, b_f, nullptr, fbuf, DS);
  // gin = f @ W_ih^T + (b_ih + b_hh) -> bf16 gate-interleaved, NT=2
  k_gemm2<0,1,2,2><<<dim3(NROWS/64, 8), 256, 0, stream>>>(fbuf, DS, DS, fbuf, DS, 0, wih_bf, b_ih, b_hh, gin2, 1024);
  // full-W single-block LSTM (plain launch, no communication)
  k_lstm_full<<<4, 1024, 0, stream>>>(gin2, W_hh, hx, cx, hhist);
  // p = sigmoid(h . W_p + b_p)
  k_pout<<<NROWS/4, 256, 0, stream>>>(hhist, W_p, b_p, out);
}

// Round 14
// 1043.454 us; speedup vs baseline: 2.2249x; 2.2249x over previous
//
#include <hip/hip_runtime.h>
#include <hip/hip_bf16.h>

#define BS 64
#define SEQ 200
#define NSK 4096
#define DS 256
#define SM 64
#define NROWS (BS*SEQ)
#define LBLK 8   // 4 independent pairs x 2 blocks

typedef __attribute__((ext_vector_type(8))) short bf16x8;
typedef __attribute__((ext_vector_type(4))) float f32x4;
typedef unsigned long long u64;

__device__ __forceinline__ float sigf(float x){ return 1.0f/(1.0f+expf(-x)); }
__device__ __forceinline__ float fast_sig(float x){ return 1.0f/(1.0f+__expf(-x)); }
__device__ __forceinline__ float fast_tanh(float x){
  float t = __expf(-2.0f*fabsf(x));
  float r = (1.0f - t)/(1.0f + t);
  return copysignf(r, x);
}
__device__ __forceinline__ short f2bf(float x){
  unsigned int u = __float_as_uint(x);
  unsigned int r = (u + 0x7fffu + ((u >> 16) & 1u)) >> 16;
  return (short)r;
}
__device__ __forceinline__ float bf2f(unsigned short s){
  return __uint_as_float(((unsigned int)s) << 16);
}

// ---------------- Kernel A: gather k,v + attention softmax w ----------------
__global__ __launch_bounds__(256) void k_gather_attn(
    const int* __restrict__ q, const int* __restrict__ r,
    const float* __restrict__ k_emb, const float* __restrict__ x_emb,
    const float* __restrict__ Mk,
    float* __restrict__ X2, float* __restrict__ vbuf, float* __restrict__ wbuf)
{
  __shared__ float ks[4][DS];
  const int tid = threadIdx.x;
  const int wv = tid >> 6, ln = tid & 63;
  const int row = blockIdx.x * 4 + wv;
  const int b = row / SEQ, s = row % SEQ;
  const int qi = q[b*SEQ + s];
  const int ri = r[b*SEQ + s];
  const float4* kr = (const float4*)(k_emb + (size_t)qi * DS);
  const float4* vr = (const float4*)(x_emb + ((size_t)qi + (size_t)NSK * ri) * DS);
  float4 kv = kr[ln];
  float4 vv = vr[ln];
  ((float4*)(X2 + (size_t)row*512 + DS))[ln] = kv;
  ((float4*)(vbuf + (size_t)row*DS))[ln] = vv;
  *((float4*)&ks[wv][ln*4]) = kv;
  __syncthreads();
  const float4* mkr = (const float4*)(Mk + (size_t)ln * DS);
  float a0=0.f,a1=0.f,a2=0.f,a3=0.f;
  #pragma unroll 8
  for (int d4=0; d4<DS/4; d4++){
    float4 m4 = mkr[d4];
    float4 k4 = *((const float4*)&ks[wv][d4*4]);
    a0 += m4.x*k4.x; a1 += m4.y*k4.y; a2 += m4.z*k4.z; a3 += m4.w*k4.w;
  }
  float lg = (a0+a1)+(a2+a3);
  float mx = lg;
  #pragma unroll
  for (int off=32; off; off>>=1) mx = fmaxf(mx, __shfl_xor(mx, off));
  float ex = expf(lg - mx);
  float sm = ex;
  #pragma unroll
  for (int off=32; off; off>>=1) sm += __shfl_xor(sm, off);
  wbuf[(size_t)row*SM + ln] = ex / sm;
}

// ---------------- bf16 MFMA GEMM: C = act(A @ W^T + bias [+bias2]) ----------
// ABF: A is bf16 (else f32). OUT: 0 f32 linear, 1 bf16 linear, 2 bf16 gate-
// interleaved ([m][ (n&255)*4 + (n>>8) ], for the LSTM's gin layout).
template<int ACT, int ABF, int OUT>
__global__ __launch_bounds__(256) void k_gemm2(
    const void* __restrict__ A0, int lda0, int K0,
    const void* __restrict__ A1, int lda1, int K1,
    const float* __restrict__ W, const float* __restrict__ bias,
    const float* __restrict__ bias2,
    void* __restrict__ C, int N)
{
  const int K = K0 + K1;
  __shared__ __align__(16) char As[64*80];
  __shared__ __align__(16) char Bs[64*80];
  const int tid = threadIdx.x;
  const int l = tid & 63, w = tid >> 6;
  const int m0 = blockIdx.x * 64, n0 = blockIdx.y * 64;
  const int mh = w >> 1, nh = w & 1;
  const int srow = tid >> 2, sseg = tid & 3;

  f32x4 acc[2][2];
  #pragma unroll
  for (int i=0;i<2;i++)
    #pragma unroll
    for (int j=0;j<2;j++) acc[i][j] = (f32x4){0.f,0.f,0.f,0.f};

  for (int k0=0; k0<K; k0+=32){
    const int kk = k0 + sseg*8;
    bf16x8 av;
    if (ABF){
      const ushort* ap = (kk < K0) ? (const ushort*)A0 + (size_t)(m0+srow)*lda0 + kk
                                   : (const ushort*)A1 + (size_t)(m0+srow)*lda1 + (kk-K0);
      av = *(const bf16x8*)ap;
    } else {
      const float* ap = (kk < K0) ? (const float*)A0 + (size_t)(m0+srow)*lda0 + kk
                                  : (const float*)A1 + (size_t)(m0+srow)*lda1 + (kk-K0);
      float4 a1 = *(const float4*)ap;
      float4 a2 = *(const float4*)(ap+4);
      av[0]=f2bf(a1.x); av[1]=f2bf(a1.y); av[2]=f2bf(a1.z); av[3]=f2bf(a1.w);
      av[4]=f2bf(a2.x); av[5]=f2bf(a2.y); av[6]=f2bf(a2.z); av[7]=f2bf(a2.w);
    }
    *(bf16x8*)(As + srow*80 + ((sseg ^ (srow&3))*16)) = av;
    const float* wp = W + (size_t)(n0+srow)*K + kk;
    float4 b1 = *(const float4*)wp;
    float4 b2 = *(const float4*)(wp+4);
    bf16x8 bv;
    bv[0]=f2bf(b1.x); bv[1]=f2bf(b1.y); bv[2]=f2bf(b1.z); bv[3]=f2bf(b1.w);
    bv[4]=f2bf(b2.x); bv[5]=f2bf(b2.y); bv[6]=f2bf(b2.z); bv[7]=f2bf(b2.w);
    *(bf16x8*)(Bs + srow*80 + ((sseg ^ (srow&3))*16)) = bv;
    __syncthreads();
    bf16x8 af[2], bf[2];
    #pragma unroll
    for (int mi=0; mi<2; mi++){
      const int row = mh*32 + mi*16 + (l&15);
      af[mi] = *(const bf16x8*)(As + row*80 + (((l>>4) ^ (row&3))*16));
    }
    #pragma unroll
    for (int ni=0; ni<2; ni++){
      const int row = nh*32 + ni*16 + (l&15);
      bf[ni] = *(const bf16x8*)(Bs + row*80 + (((l>>4) ^ (row&3))*16));
    }
    #pragma unroll
    for (int mi=0; mi<2; mi++)
      #pragma unroll
      for (int ni=0; ni<2; ni++)
        acc[mi][ni] = __builtin_amdgcn_mfma_f32_16x16x32_bf16(af[mi], bf[ni], acc[mi][ni], 0,0,0);
    __syncthreads();
  }
  #pragma unroll
  for (int mi=0; mi<2; mi++){
    #pragma unroll
    for (int ni=0; ni<2; ni++){
      const int n = n0 + nh*32 + ni*16 + (l&15);
      float bsum = bias[n] + (bias2 ? bias2[n] : 0.f);
      #pragma unroll
      for (int j=0;j<4;j++){
        const int m = m0 + mh*32 + mi*16 + (l>>4)*4 + j;
        float v = acc[mi][ni][j] + bsum;
        if (ACT==1) v = sigf(v);
        else if (ACT==2) v = tanhf(v);
        if (OUT==0)      ((float*)C)[(size_t)m*N + n] = v;
        else if (OUT==1) ((ushort*)C)[(size_t)m*N + n] = (ushort)f2bf(v);
        else             ((ushort*)C)[(size_t)m*N + ((n&255)*4 + (n>>8))] = (ushort)f2bf(v);
      }
    }
  }
}

// ---------------- fused erase/add GEMM (shared A = webuf bf16) --------------
__global__ __launch_bounds__(256) void k_gemm_ea(
    const ushort* __restrict__ A, const float* __restrict__ W_e,
    const float* __restrict__ b_e, const float* __restrict__ W_add,
    const float* __restrict__ b_add,
    float* __restrict__ ebuf, float* __restrict__ abuf)
{
  __shared__ __align__(16) char As[64*80];
  __shared__ __align__(16) char Bse[64*80];
  __shared__ __align__(16) char Bsa[64*80];
  const int tid = threadIdx.x;
  const int l = tid & 63, w = tid >> 6;
  const int m0 = blockIdx.x * 64, n0 = blockIdx.y * 64;
  const int mh = w >> 1, nh = w & 1;
  const int srow = tid >> 2, sseg = tid & 3;

  f32x4 acce[2][2], acca[2][2];
  #pragma unroll
  for (int i=0;i<2;i++)
    #pragma unroll
    for (int j=0;j<2;j++){ acce[i][j]=(f32x4){0.f,0.f,0.f,0.f}; acca[i][j]=(f32x4){0.f,0.f,0.f,0.f}; }

  for (int k0=0; k0<DS; k0+=32){
    const int kk = k0 + sseg*8;
    bf16x8 av = *(const bf16x8*)(A + (size_t)(m0+srow)*DS + kk);
    *(bf16x8*)(As + srow*80 + ((sseg ^ (srow&3))*16)) = av;
    {
      const float* wp = W_e + (size_t)(n0+srow)*DS + kk;
      float4 b1 = *(const float4*)wp; float4 b2 = *(const float4*)(wp+4);
      bf16x8 bv;
      bv[0]=f2bf(b1.x); bv[1]=f2bf(b1.y); bv[2]=f2bf(b1.z); bv[3]=f2bf(b1.w);
      bv[4]=f2bf(b2.x); bv[5]=f2bf(b2.y); bv[6]=f2bf(b2.z); bv[7]=f2bf(b2.w);
      *(bf16x8*)(Bse + srow*80 + ((sseg ^ (srow&3))*16)) = bv;
    }
    {
      const float* wp = W_add + (size_t)(n0+srow)*DS + kk;
      float4 b1 = *(const float4*)wp; float4 b2 = *(const float4*)(wp+4);
      bf16x8 bv;
      bv[0]=f2bf(b1.x); bv[1]=f2bf(b1.y); bv[2]=f2bf(b1.z); bv[3]=f2bf(b1.w);
      bv[4]=f2bf(b2.x); bv[5]=f2bf(b2.y); bv[6]=f2bf(b2.z); bv[7]=f2bf(b2.w);
      *(bf16x8*)(Bsa + srow*80 + ((sseg ^ (srow&3))*16)) = bv;
    }
    __syncthreads();
    bf16x8 af[2], bfe[2], bfa[2];
    #pragma unroll
    for (int mi=0; mi<2; mi++){
      const int row = mh*32 + mi*16 + (l&15);
      af[mi] = *(const bf16x8*)(As + row*80 + (((l>>4) ^ (row&3))*16));
    }
    #pragma unroll
    for (int ni=0; ni<2; ni++){
      const int row = nh*32 + ni*16 + (l&15);
      bfe[ni] = *(const bf16x8*)(Bse + row*80 + (((l>>4) ^ (row&3))*16));
      bfa[ni] = *(const bf16x8*)(Bsa + row*80 + (((l>>4) ^ (row&3))*16));
    }
    #pragma unroll
    for (int mi=0; mi<2; mi++)
      #pragma unroll
      for (int ni=0; ni<2; ni++){
        acce[mi][ni] = __builtin_amdgcn_mfma_f32_16x16x32_bf16(af[mi], bfe[ni], acce[mi][ni], 0,0,0);
        acca[mi][ni] = __builtin_amdgcn_mfma_f32_16x16x32_bf16(af[mi], bfa[ni], acca[mi][ni], 0,0,0);
      }
    __syncthreads();
  }
  #pragma unroll
  for (int mi=0; mi<2; mi++){
    #pragma unroll
    for (int ni=0; ni<2; ni++){
      const int n = n0 + nh*32 + ni*16 + (l&15);
      const float be = b_e[n], ba = b_add[n];
      #pragma unroll
      for (int j=0;j<4;j++){
        const int m = m0 + mh*32 + mi*16 + (l>>4)*4 + j;
        ebuf[(size_t)m*DS + n] = sigf(acce[mi][ni][j] + be);
        abuf[(size_t)m*DS + n] = tanhf(acca[mi][ni][j] + ba);
      }
    }
  }
}

// ---------------- Memory scan (sequential over t) ---------------------------
__global__ __launch_bounds__(256) void k_scan(
    const float* __restrict__ wbuf, const float* __restrict__ ebuf,
    const float* __restrict__ abuf, const float* __restrict__ Mv0,
    float* __restrict__ X2)
{
  const int b = blockIdx.x;
  const int d = threadIdx.x;
  __shared__ float ws[SM];
  float mem[SM];
  #pragma unroll
  for (int m=0;m<SM;m++) mem[m] = Mv0[m*DS + d];
  for (int t=0;t<SEQ;t++){
    const size_t row = (size_t)b*SEQ + t;
    if (d < SM) ws[d] = wbuf[row*SM + d];
    const float e = ebuf[row*DS + d];
    const float a = abuf[row*DS + d];
    __syncthreads();
    float r0=0.f,r1=0.f,r2=0.f,r3=0.f;
    #pragma unroll
    for (int m=0;m<SM;m+=4){
      float w0=ws[m], w1=ws[m+1], w2=ws[m+2], w3=ws[m+3];
      r0 += w0*mem[m];   mem[m]   += w0*fmaf(-e, mem[m],   a);
      r1 += w1*mem[m+1]; mem[m+1] += w1*fmaf(-e, mem[m+1], a);
      r2 += w2*mem[m+2]; mem[m+2] += w2*fmaf(-e, mem[m+2], a);
      r3 += w3*mem[m+3]; mem[m+3] += w3*fmaf(-e, mem[m+3], a);
    }
    X2[row*512 + d] = (r0+r1)+(r2+r3);
    __syncthreads();
  }
}

// ---------------- Pairwise cooperative MFMA LSTM (tagged-slot exchange) -----
// Proven configuration (R9: 645us LSTM, 1039us total, VGPR=128). 8 blocks =
// 4 pairs; pair p owns batches [16p,+16); block ro owns dims [128ro,+128) with
// all 4 gates = 32 B-frags/wave = exactly the 128-VGPR clean footprint (the
// per-SIMD pool is 512 regs; 4 waves/SIMD x 128 = full). Cross-block h
// exchange via 64-bit agent-scope tagged slots (data+flag in one word).
__global__ __launch_bounds__(512, 2) void k_lstm2(
    const ushort* __restrict__ gin2, const float* __restrict__ W_hh,
    const float* __restrict__ hx, const float* __restrict__ cx,
    short* __restrict__ hhist, unsigned long long* __restrict__ xbuf)
{
  const int bb = blockIdx.x;
  const int p  = bb >> 1;
  const int ro = bb & 1;
  const int tid = threadIdx.x;
  const int l   = tid & 63;
  const int w   = tid >> 6;

  __shared__ short hsm[2][16*256];   // 2 x 8KB, 512B rows, XOR-swizzled

  bf16x8 wfr[4][8];
  {
    const int col  = l & 15;
    const int krow = (l >> 4) * 8;
    #pragma unroll
    for (int gt=0; gt<4; gt++){
      const int G = gt*256 + ro*128 + w*16 + col;
      const float* wrow = W_hh + (size_t)G*256;
      #pragma unroll
      for (int kt=0; kt<8; kt++){
        const int k0 = kt*32 + krow;
        float4 wa = *(const float4*)(wrow + k0);
        float4 wb = *(const float4*)(wrow + k0 + 4);
        bf16x8 f;
        f[0]=f2bf(wa.x); f[1]=f2bf(wa.y); f[2]=f2bf(wa.z); f[3]=f2bf(wa.w);
        f[4]=f2bf(wb.x); f[5]=f2bf(wb.y); f[6]=f2bf(wb.z); f[7]=f2bf(wb.w);
        wfr[gt][kt] = f;
      }
    }
  }

  const int dhalf = w*16 + (l & 15);           // 0..127 within my half
  const int gdim  = ro*128 + dhalf;            // this lane's dim
  float c_[4];
  {
    float c0 = cx[gdim];
    #pragma unroll
    for (int r=0;r<4;r++) c_[r] = c0;
  }

  // stage hx into hsm[0] (full 256 dims, 16 rows)
  if (tid < 256){
    const int row = tid >> 4, seg = tid & 15;
    #pragma unroll
    for (int u=0; u<2; u++){
      const int kb = seg*32 + u*16;
      const int d0 = kb >> 1;
      float4 ha = *(const float4*)(hx + d0);
      float4 hb = *(const float4*)(hx + d0 + 4);
      bf16x8 v;
      v[0]=f2bf(ha.x); v[1]=f2bf(ha.y); v[2]=f2bf(ha.z); v[3]=f2bf(ha.w);
      v[4]=f2bf(hb.x); v[5]=f2bf(hb.y); v[6]=f2bf(hb.z); v[7]=f2bf(hb.w);
      *(bf16x8*)((char*)hsm[0] + row*512 + (kb ^ ((row&7)<<4))) = v;
    }
  }

  // prefetch gin[t=0]: one u64 per batch = all 4 gates for this lane's dim
  u64 gpre[4];
  #pragma unroll
  for (int r=0; r<4; r++){
    const int b = p*16 + (l>>4)*4 + r;
    gpre[r] = *(const u64*)(gin2 + ((size_t)(b*SEQ))*1024 + gdim*4);
  }

  // slot buffers: xbuf[(p*2+ro)*1024 + bat*64 + (dhalf>>1)]
  unsigned long long* myslots = xbuf + (size_t)(p*2 + ro)*1024;
  unsigned long long* pslots  = xbuf + (size_t)(p*2 + (1-ro))*1024;

  for (int t=0; t<SEQ; t++){
    __syncthreads();   // hsm[t&1] fully staged
    const int cur = t & 1;

    f32x4 acc[4];
    #pragma unroll
    for (int gt=0; gt<4; gt++) acc[gt] = (f32x4){0.f,0.f,0.f,0.f};
    const int r0 = l & 15;
    #pragma unroll
    for (int kt=0; kt<8; kt++){
      const int kbyte = kt*64 + (l>>4)*16;
      bf16x8 a = *(const bf16x8*)((const char*)hsm[cur] + r0*512 + (kbyte ^ ((r0&7)<<4)));
      #pragma unroll
      for (int gt=0; gt<4; gt++)
        acc[gt] = __builtin_amdgcn_mfma_f32_16x16x32_bf16(a, wfr[gt][kt], acc[gt], 0,0,0);
    }

    const unsigned int tag = (unsigned int)(t + 1);
    #pragma unroll
    for (int r=0; r<4; r++){
      const int bat = (l>>4)*4 + r;            // block-local batch
      const int b = p*16 + bat;
      const u64 gv = gpre[r];
      float iv = acc[0][r] + bf2f((unsigned short)(gv       & 0xffffu));
      float fv = acc[1][r] + bf2f((unsigned short)((gv>>16) & 0xffffu));
      float gg = acc[2][r] + bf2f((unsigned short)((gv>>32) & 0xffffu));
      float ov = acc[3][r] + bf2f((unsigned short)((gv>>48) & 0xffffu));
      float cc = fast_sig(fv)*c_[r] + fast_sig(iv)*fast_tanh(gg);
      c_[r] = cc;
      float h = fast_sig(ov)*fast_tanh(cc);
      unsigned short hb = (unsigned short)f2bf(h);
      hhist[((size_t)(b*SEQ + t))*256 + gdim] = (short)hb;   // plain; read post-kernel
      *(short*)((char*)hsm[cur^1] + bat*512 + ((gdim*2) ^ ((bat&7)<<4))) = (short)hb;
      // tagged-slot export (even-dim lanes pack self + neighbor)
      unsigned short nb = (unsigned short)__shfl_xor((int)hb, 1);
      if ((l & 1) == 0){
        unsigned long long v = ((unsigned long long)hb << 48)
                             | ((unsigned long long)nb << 32)
                             | (unsigned long long)tag;
        __hip_atomic_store(&myslots[bat*64 + (dhalf>>1)], v,
                           __ATOMIC_RELAXED, __HIP_MEMORY_SCOPE_AGENT);
      }
    }

    if (t == SEQ-1) break;

    // prefetch gin[t+1] while our stores propagate
    #pragma unroll
    for (int r=0; r<4; r++){
      const int b = p*16 + (l>>4)*4 + r;
      gpre[r] = *(const u64*)(gin2 + ((size_t)(b*SEQ + t+1))*1024 + gdim*4);
    }

    // poll partner's 2 slots; write partner half into hsm[cur^1]
    {
      const int s0 = tid*2, s1 = tid*2 + 1;
      unsigned long long v0=0, v1=0;
      bool ok0=false, ok1=false;
      while (true){
        if (!ok0){ v0 = __hip_atomic_load(&pslots[s0], __ATOMIC_RELAXED, __HIP_MEMORY_SCOPE_AGENT);
                   ok0 = ((unsigned int)v0 == tag); }
        if (!ok1){ v1 = __hip_atomic_load(&pslots[s1], __ATOMIC_RELAXED, __HIP_MEMORY_SCOPE_AGENT);
                   ok1 = ((unsigned int)v1 == tag); }
        if (ok0 && ok1) break;
        __builtin_amdgcn_s_sleep(1);
      }
      #pragma unroll
      for (int u=0; u<2; u++){
        unsigned long long v = u ? v1 : v0;
        const int sid = u ? s1 : s0;
        const int bat = sid >> 6;
        const int dp  = sid & 63;
        const int dpart = (1-ro)*128 + dp*2;
        unsigned int wv = (unsigned int)((v >> 48) & 0xffffu)
                        | (((unsigned int)(v >> 32) & 0xffffu) << 16);
        *(unsigned int*)((char*)hsm[cur^1] + bat*512 + ((dpart*2) ^ ((bat&7)<<4))) = wv;
      }
    }
    // next-iteration top __syncthreads covers LDS visibility
  }
}

// ---------------- p output: sigmoid(h . W_p + b_p) --------------------------
__global__ __launch_bounds__(256) void k_pout(
    const short* __restrict__ hhist, const float* __restrict__ W_p,
    const float* __restrict__ b_p, float* __restrict__ out)
{
  const int tid = threadIdx.x;
  const int row = blockIdx.x*4 + (tid>>6);
  const int ln = tid & 63;
  ushort4 hv = ((const ushort4*)(hhist + (size_t)row*256))[ln];
  float4 wp = ((const float4*)W_p)[ln];
  float s = bf2f(hv.x)*wp.x + bf2f(hv.y)*wp.y + bf2f(hv.z)*wp.z + bf2f(hv.w)*wp.w;
  #pragma unroll
  for (int off=32; off; off>>=1) s += __shfl_xor(s, off);
  if (ln == 0) out[row] = sigf(s + b_p[0]);
}

extern "C" void kernel_launch(void* const* d_in, const int* in_sizes, int n_in,
                              void* d_out, int out_size, void* d_ws, size_t ws_size,
                              hipStream_t stream)
{
  const int*   q     = (const int*)d_in[0];
  const int*   r     = (const int*)d_in[1];
  const float* k_emb = (const float*)d_in[2];
  const float* x_emb = (const float*)d_in[3];
  const float* Mk    = (const float*)d_in[4];
  const float* Mv0   = (const float*)d_in[5];
  const float* W_a   = (const float*)d_in[6];
  const float* b_a   = (const float*)d_in[7];
  const float* W_e   = (const float*)d_in[8];
  const float* b_e   = (const float*)d_in[9];
  const float* W_add = (const float*)d_in[10];
  const float* b_add = (const float*)d_in[11];
  const float* W_f   = (const float*)d_in[12];
  const float* b_f   = (const float*)d_in[13];
  const float* hx    = (const float*)d_in[14];
  const float* cx    = (const float*)d_in[15];
  const float* W_ih  = (const float*)d_in[16];
  const float* b_ih  = (const float*)d_in[17];
  const float* W_hh  = (const float*)d_in[18];
  const float* b_hh  = (const float*)d_in[19];
  const float* W_p   = (const float*)d_in[20];
  const float* b_p   = (const float*)d_in[21];
  float* out = (float*)d_out;

  // byte-offset workspace layout
  char* base = (char*)d_ws;
  float*  vbuf  = (float*)(base);                          // 13.1MB
  ushort* webuf = (ushort*)(base + 13107200);              // 6.55MB
  float*  ebuf  = (float*)(base + 19660800);               // 13.1MB
  float*  abuf  = (float*)(base + 32768000);               // 13.1MB
  float*  X2    = (float*)(base + 45875200);               // 26.2MB [reads|k]
  float*  wbuf  = (float*)(base + 72089600);               // 3.3MB
  ushort* fbuf  = (ushort*)(base + 75366400);              // 6.55MB
  ushort* gin2  = (ushort*)(base);                         // 26.2MB overlay (vbuf..ebuf dead)
  short*  hhist = (short*)fbuf;                            // overlay (fbuf dead post-gin)
  u64*    xbuf  = (u64*)(base + 81920000);                 // 64KB fresh

  k_gather_attn<<<NROWS/4, 256, 0, stream>>>(q, r, k_emb, x_emb, Mk, X2, vbuf, wbuf);
  // we = [k|v] @ W_a^T + b_a  -> bf16
  k_gemm2<0,0,1><<<dim3(NROWS/64, 4), 256, 0, stream>>>(X2+DS, 512, DS, vbuf, DS, DS, W_a, b_a, nullptr, webuf, DS);
  // erase/add fused (A = webuf bf16)
  k_gemm_ea<<<dim3(NROWS/64, 4), 256, 0, stream>>>(webuf, W_e, b_e, W_add, b_add, ebuf, abuf);
  // memory scan -> reads into X2[:,0:256]
  k_scan<<<BS, DS, 0, stream>>>(wbuf, ebuf, abuf, Mv0, X2);
  // f = tanh([reads|k] @ W_f^T + b_f) -> bf16
  k_gemm2<2,0,1><<<dim3(NROWS/64, 4), 256, 0, stream>>>(X2, 512, DS, X2+DS, 512, DS, W_f, b_f, nullptr, fbuf, DS);
  // gin = f @ W_ih^T + (b_ih + b_hh) -> bf16 gate-interleaved
  k_gemm2<0,1,2><<<dim3(NROWS/64, 16), 256, 0, stream>>>(fbuf, DS, DS, fbuf, DS, 0, W_ih, b_ih, b_hh, gin2, 1024);
  // pairwise tagged-slot LSTM (proven R9 structure)
  {
    const ushort* gin_c = gin2;
    void* args[] = { (void*)&gin_c, (void*)&W_hh, (void*)&hx, (void*)&cx,
                     (void*)&hhist, (void*)&xbuf };
    hipLaunchCooperativeKernel((void*)k_lstm2, dim3(LBLK), dim3(512), args, 0, stream);
  }
  // p = sigmoid(h . W_p + b_p)
  k_pout<<<NROWS/4, 256, 0, stream>>>(hhist, W_p, b_p, out);
}